// Round 4
// baseline (131.935 us; speedup 1.0000x reference)
//
#include <hip/hip_runtime.h>

// OpenBoundary neighbor list, N=8192, cutoff=5.0, max_neighbours=32.
// Outputs (int32, concatenated): to_idx[8192][32] | cell_indices[8192][32][3]=0 | actual_max (scalar)
//
// R4: fully branchless inner loop. Invalid lanes store to a private dump
// dword in this block's cell_indices slice (zeroed after the loop). Per-row
// state pinned to SGPRs via readfirstlane. 256-thr blocks, R=2 rows/wave,
// 1024 blocks (4/CU, 16 waves/CU), 32KB LDS j-tiles.

constexpr int   N     = 8192;
constexpr int   MAXNB = 32;
constexpr float CUT2  = 25.0f;          // 5.0^2 exactly representable
constexpr int   BLOCK = 256;            // 4 waves
constexpr int   R     = 2;              // rows per wave
constexpr int   RPB   = (BLOCK / 64) * R;   // 8 rows per block
constexpr int   T     = 2048;           // points per LDS tile (32 KB)
constexpr int   NT    = N / T;          // 4 tiles

__global__ __launch_bounds__(BLOCK, 4) void neigh_kernel(const float* __restrict__ pos,
                                                         int* __restrict__ out) {
    __shared__ float4 s4[T];            // padded xyz_, 32 KB

    const int lane = threadIdx.x & 63;

    int* __restrict__ cell    = out + N * MAXNB;                   // -> zeros
    int* __restrict__ out_max = out + N * MAXNB + N * MAXNB * 3;   // scalar

    // Wave-uniform row block; readfirstlane pins the derived state to SGPRs.
    const int row0 = __builtin_amdgcn_readfirstlane(
        (int)(blockIdx.x * RPB) + (int)(threadIdx.x >> 6) * R);
    const int schunk = row0 >> 6;       // R=2, row0 even -> both rows share it

    float xi[R], yi[R], zi[R];
    int   sbase[R], bound[R], iu[R];
    unsigned long long sbits[R];
    #pragma unroll
    for (int r = 0; r < R; ++r) {
        const int i = row0 + r;
        iu[r]    = i;
        xi[r]    = pos[3 * i + 0];
        yi[r]    = pos[3 * i + 1];
        zi[r]    = pos[3 * i + 2];
        sbase[r] = i * MAXNB;           // base + running count
        bound[r] = i * MAXNB + MAXNB;
        sbits[r] = ~(1ull << (i & 63)); // clear-self bit
    }

    // Per-thread private dump slot inside this block's cell_indices slice.
    const int dump = N * MAXNB + (int)blockIdx.x * (RPB * MAXNB * 3) + (int)threadIdx.x;

    for (int tile = 0; tile < NT; ++tile) {
        if (tile) __syncthreads();      // done reading previous tile
        for (int p = threadIdx.x; p < T; p += BLOCK) {
            const int g = tile * T + p;
            s4[p] = make_float4(pos[3 * g], pos[3 * g + 1], pos[3 * g + 2], 0.0f);
        }
        __syncthreads();

        const int jb0 = tile * T;
        float4 cur = s4[lane];          // register double-buffer
        for (int b = 0; b < T; b += 64) {
            const float4 nxt = s4[((b + 64 < T) ? (b + 64) : 0) + lane];
            const int  jv = jb0 + b + lane;
            const bool selfchunk = ((jb0 + b) >> 6) == schunk;   // uniform
            #pragma unroll
            for (int r = 0; r < R; ++r) {
                // numpy f32 rounding: no FMA contraction, ((dx^2+dy^2)+dz^2)
                const float dx = __fsub_rn(xi[r], cur.x);
                const float dy = __fsub_rn(yi[r], cur.y);
                const float dz = __fsub_rn(zi[r], cur.z);
                const float r2 = __fadd_rn(__fadd_rn(__fmul_rn(dx, dx), __fmul_rn(dy, dy)),
                                           __fmul_rn(dz, dz));
                const bool inr = (r2 <= CUT2);
                unsigned long long m = __ballot(inr);
                m &= selfchunk ? sbits[r] : ~0ull;               // s_cselect + s_and
                const int pre = __builtin_amdgcn_mbcnt_hi(
                    (unsigned int)(m >> 32),
                    __builtin_amdgcn_mbcnt_lo((unsigned int)m, 0u));
                const int  off   = sbase[r] + pre;
                const bool valid = inr & (jv != iu[r]) & (off < bound[r]);
                out[valid ? off : dump] = jv;                    // unconditional store
                sbase[r] += __popcll(m);                         // s_bcnt1 + s_add
            }
            cur = nxt;
        }
    }

    __syncthreads();                    // all dumps from this block drained
    {   // Zero this block's cell_indices slice (includes the dump dwords).
        int* c = cell + (size_t)blockIdx.x * (RPB * MAXNB * 3);
        for (int t = threadIdx.x; t < RPB * MAXNB * 3; t += BLOCK) c[t] = 0;
    }

    // Fill unused to_idx slots with -1; scalar = max full (unclamped) count.
    int mx = 0;
    #pragma unroll
    for (int r = 0; r < R; ++r) {
        const int count = sbase[r] - iu[r] * MAXNB;
        if (lane >= count && lane < MAXNB) out[iu[r] * MAXNB + lane] = -1;
        mx = max(mx, count);
    }
    if (lane == 0) atomicMax(out_max, mx);   // poison/0 in slot is <= 0: valid identity
}

extern "C" void kernel_launch(void* const* d_in, const int* in_sizes, int n_in,
                              void* d_out, int out_size, void* d_ws, size_t ws_size,
                              hipStream_t stream) {
    const float* pos = (const float*)d_in[0];   // [8192, 3] f32
    int* out = (int*)d_out;

    const int grid = N / RPB;                   // 1024 blocks = 4/CU
    neigh_kernel<<<grid, BLOCK, 0, stream>>>(pos, out);
}